// Round 2
// baseline (350.569 us; speedup 1.0000x reference)
//
#include <hip/hip_runtime.h>
#include <math.h>

#define NN 50000
#define DIN 256
#define HC 64
#define NEG 0.2f
#define TM 64
#define NB 196          // ceil(NN/256) coarse buckets (dst >> 8)
#define EPB 4096        // edges per bin_k block
#define CAP 36864       // bsort LDS staging capacity

typedef short bf16x8 __attribute__((ext_vector_type(8)));
typedef unsigned short ush8 __attribute__((ext_vector_type(8)));
typedef float f32x4 __attribute__((ext_vector_type(4)));

// fp32 -> bf16 round-to-nearest-even
__device__ __forceinline__ unsigned short f2bf(float x) {
    unsigned u = __float_as_uint(x);
    u += 0x7FFFu + ((u >> 16) & 1u);
    return (unsigned short)(u >> 16);
}
__device__ __forceinline__ float bf2f(unsigned short h) {
    return __uint_as_float((unsigned)h << 16);
}

// ---- DPP cross-lane add helper ----
template <int CTRL>
__device__ __forceinline__ float dpp_mov(float x) {
    int r = __builtin_amdgcn_update_dpp(0, __float_as_int(x), CTRL, 0xF, 0xF, true);
    return __int_as_float(r);
}

// ---------------- CSR build: bucketed counting sort ----------------

__global__ __launch_bounds__(256) void bhist_k(const int* __restrict__ dst,
                                               int* __restrict__ bcnt, int E) {
    __shared__ int h[NB];
    int t = threadIdx.x;
    for (int i = t; i < NB; i += 256) h[i] = 0;
    __syncthreads();
    int base = blockIdx.x * 2048 + t;
#pragma unroll
    for (int k = 0; k < 8; ++k) {
        int e = base + k * 256;
        if (e < E) atomicAdd(&h[dst[e] >> 8], 1);
    }
    __syncthreads();
    for (int i = t; i < NB; i += 256)
        if (h[i]) atomicAdd(&bcnt[i], h[i]);
}

__global__ __launch_bounds__(256) void bscan_k(const int* __restrict__ bcnt,
                                               int* __restrict__ boffs,
                                               int* __restrict__ bcursor,
                                               int* __restrict__ offs, int E) {
    __shared__ int s[256];
    int t = threadIdx.x;
    s[t] = (t < NB) ? bcnt[t] : 0;
    __syncthreads();
    for (int off = 1; off < 256; off <<= 1) {
        int v = s[t];
        int u = (t >= off) ? s[t - off] : 0;
        __syncthreads();
        s[t] = v + u;
        __syncthreads();
    }
    if (t < NB) {
        int ex = (t == 0) ? 0 : s[t - 1];
        boffs[t] = ex;
        bcursor[t] = ex;
    }
    if (t == NB) boffs[NB] = s[NB - 1];
    if (t == 0) offs[NN] = E;
}

__global__ __launch_bounds__(1024) void bin_k(const int* __restrict__ src,
                                              const int* __restrict__ dst,
                                              int* __restrict__ bcursor,
                                              unsigned* __restrict__ epair, int E) {
    __shared__ int hist[NB];
    __shared__ int lofs[NB];
    __shared__ int gshift[NB];
    __shared__ int scanb[256];
    __shared__ unsigned pbuf[EPB];
    __shared__ unsigned char abkt[EPB];
    int t = threadIdx.x;
    for (int i = t; i < NB; i += 1024) hist[i] = 0;
    __syncthreads();
    int e0 = blockIdx.x * EPB;
    unsigned p[4]; int bk[4], rk[4]; bool val[4];
#pragma unroll
    for (int k = 0; k < 4; ++k) {
        int e = e0 + k * 1024 + t;
        val[k] = e < E;
        if (val[k]) {
            int s = src[e], d = dst[e];
            p[k] = ((unsigned)s << 8) | (unsigned)(d & 255);
            bk[k] = d >> 8;
            rk[k] = atomicAdd(&hist[bk[k]], 1);
        }
    }
    __syncthreads();
    if (t < 256) scanb[t] = (t < NB) ? hist[t] : 0;
    __syncthreads();
    for (int off = 1; off < 256; off <<= 1) {
        int v = 0, u = 0;
        if (t < 256) { v = scanb[t]; if (t >= off) u = scanb[t - off]; }
        __syncthreads();
        if (t < 256) scanb[t] = v + u;
        __syncthreads();
    }
    if (t < NB) {
        int ex = (t == 0) ? 0 : scanb[t - 1];
        lofs[t] = ex;
        int gb = atomicAdd(&bcursor[t], hist[t]);
        gshift[t] = gb - ex;
    }
    __syncthreads();
    int total = scanb[NB - 1];
#pragma unroll
    for (int k = 0; k < 4; ++k) {
        if (val[k]) {
            int pos = lofs[bk[k]] + rk[k];
            pbuf[pos] = p[k];
            abkt[pos] = (unsigned char)bk[k];
        }
    }
    __syncthreads();
    for (int i = t; i < total; i += 1024) {
        int b = abkt[i];
        epair[gshift[b] + i] = pbuf[i];
    }
}

// per-bucket counting sort; ssrc holds BYTE offsets (src*HC*4 == src<<8)
__global__ __launch_bounds__(1024) void bsort_k(const unsigned* __restrict__ epair,
                                                const int* __restrict__ boffs,
                                                int* __restrict__ offs,
                                                unsigned* __restrict__ ssrc, int n) {
    __shared__ int lhist[256];
    __shared__ int lcur[256];
    __shared__ int scanb[256];
    __shared__ unsigned sbuf[CAP];
    int b = blockIdx.x, t = threadIdx.x;
    int start = boffs[b], end = boffs[b + 1];
    int cnt = end - start;
    if (t < 256) lhist[t] = 0;
    __syncthreads();
    for (int i = t; i < cnt; i += 1024) {
        unsigned p = epair[start + i];
        atomicAdd(&lhist[p & 255], 1);
    }
    __syncthreads();
    if (t < 256) scanb[t] = lhist[t];
    __syncthreads();
    for (int off = 1; off < 256; off <<= 1) {
        int v = 0, u = 0;
        if (t < 256) { v = scanb[t]; if (t >= off) u = scanb[t - off]; }
        __syncthreads();
        if (t < 256) scanb[t] = v + u;
        __syncthreads();
    }
    if (t < 256) {
        int ex = (t == 0) ? 0 : scanb[t - 1];
        lcur[t] = ex;
        int node = b * 256 + t;
        if (node < n) offs[node] = start + ex;
    }
    __syncthreads();
    if (cnt <= CAP) {
        for (int i = t; i < cnt; i += 1024) {
            unsigned p = epair[start + i];
            int r = atomicAdd(&lcur[p & 255], 1);
            sbuf[r] = p & ~255u;
        }
        __syncthreads();
        for (int i = t; i < cnt; i += 1024) ssrc[start + i] = sbuf[i];
    } else {
        for (int i = t; i < cnt; i += 1024) {
            unsigned p = epair[start + i];
            int r = atomicAdd(&lcur[p & 255], 1);
            ssrc[start + r] = p & ~255u;
        }
    }
}

// ---------------- weight prep: transpose + bf16 hi/lo split ----------------
__global__ __launch_bounds__(256) void wprep_dual_k(const float* __restrict__ Wl,
                                                    const float* __restrict__ Wr,
                                                    unsigned short* __restrict__ img,
                                                    int K) {
    int i = blockIdx.x * 256 + threadIdx.x;
    int total = (K >> 5) * 10240;
    if (i >= total) return;
    int kk = i % 40;
    int c  = (i / 40) & 127;
    int p  = (i / 5120) & 1;
    int s  = i / 10240;
    unsigned short v = 0;
    if (kk < 32) {
        int k = s * 32 + kk;
        float w = (c < 64) ? Wl[k * HC + c] : Wr[k * HC + (c - 64)];
        unsigned short hi = f2bf(w);
        v = p ? f2bf(w - bf2f(hi)) : hi;
    }
    img[i] = v;
}

__global__ __launch_bounds__(256) void wprep_head_k(const float* __restrict__ Wo,
                                                    unsigned short* __restrict__ img) {
    int i = blockIdx.x * 256 + threadIdx.x;
    if (i >= 40960) return;
    int kk = i % 40;
    int c  = (i / 40) & 127;
    int p  = (i / 5120) & 1;
    int s  = (i / 10240) & 1;
    int h  = i / 20480;
    unsigned short v = 0;
    if (kk < 32) {
        int k = s * 32 + kk;
        float w = Wo[k * DIN + h * 128 + c];
        unsigned short hi = f2bf(w);
        v = p ? f2bf(w - bf2f(hi)) : hi;
    }
    img[i] = v;
}

// ---------------- MFMA dual GEMM: [xl|xr] = A @ [Wl|Wr] + [bl|br] ----------
__global__ __launch_bounds__(256) void gemm_dual_mfma_k(
        const float* __restrict__ A,
        const unsigned short* __restrict__ img,
        const float* __restrict__ bl, const float* __restrict__ br,
        float* __restrict__ xl, float* __restrict__ xr,
        int n, int K) {
    __shared__ __attribute__((aligned(16))) unsigned short As[2][64][40];
    __shared__ __attribute__((aligned(16))) unsigned short Bs[2][128][40];
    int t = threadIdx.x;
    int l = t & 63, w = t >> 6;
    int wr = w >> 1, wc = w & 1;
    int lan = l & 15;
    int kb  = (l >> 4) * 8;
    int row0 = blockIdx.x * 64;
    int srow = t >> 2;
    int skq  = (t & 3) * 8;
    bool rok = (row0 + srow) < n;
    const float* aptr = A + (size_t)(row0 + srow) * K + skq;

    f32x4 acc0[4] = {}, acc1[4] = {};

    int nks = K >> 5;
    for (int ks = 0; ks < nks; ++ks) {
        __syncthreads();
        {
            const ush8* src = (const ush8*)(img + (size_t)ks * 10240);
            ush8* dst = (ush8*)&Bs[0][0][0];
            int base = w * 5 * 64 + l;
#pragma unroll
            for (int c2 = 0; c2 < 5; ++c2) {
                int u = base + c2 * 64;
                dst[u] = src[u];
            }
        }
        {
            float4 f0 = make_float4(0.f, 0.f, 0.f, 0.f), f1 = f0;
            if (rok) {
                f0 = *(const float4*)(aptr + ks * 32);
                f1 = *(const float4*)(aptr + ks * 32 + 4);
            }
            float xs[8] = {f0.x, f0.y, f0.z, f0.w, f1.x, f1.y, f1.z, f1.w};
            ush8 hi8, lo8;
#pragma unroll
            for (int j = 0; j < 8; ++j) {
                unsigned short h = f2bf(xs[j]);
                hi8[j] = h;
                lo8[j] = f2bf(xs[j] - bf2f(h));
            }
            *(ush8*)&As[0][srow][skq] = hi8;
            *(ush8*)&As[1][srow][skq] = lo8;
        }
        __syncthreads();
        bf16x8 ah0 = *(const bf16x8*)&As[0][wr * 32 + lan][kb];
        bf16x8 ah1 = *(const bf16x8*)&As[0][wr * 32 + 16 + lan][kb];
        bf16x8 al0 = *(const bf16x8*)&As[1][wr * 32 + lan][kb];
        bf16x8 al1 = *(const bf16x8*)&As[1][wr * 32 + 16 + lan][kb];
#pragma unroll
        for (int cf = 0; cf < 4; ++cf) {
            int bc = wc * 64 + cf * 16 + lan;
            bf16x8 bhv = *(const bf16x8*)&Bs[0][bc][kb];
            bf16x8 blv = *(const bf16x8*)&Bs[1][bc][kb];
            acc0[cf] = __builtin_amdgcn_mfma_f32_16x16x32_bf16(ah0, bhv, acc0[cf], 0, 0, 0);
            acc1[cf] = __builtin_amdgcn_mfma_f32_16x16x32_bf16(ah1, bhv, acc1[cf], 0, 0, 0);
            acc0[cf] = __builtin_amdgcn_mfma_f32_16x16x32_bf16(al0, bhv, acc0[cf], 0, 0, 0);
            acc1[cf] = __builtin_amdgcn_mfma_f32_16x16x32_bf16(al1, bhv, acc1[cf], 0, 0, 0);
            acc0[cf] = __builtin_amdgcn_mfma_f32_16x16x32_bf16(ah0, blv, acc0[cf], 0, 0, 0);
            acc1[cf] = __builtin_amdgcn_mfma_f32_16x16x32_bf16(ah1, blv, acc1[cf], 0, 0, 0);
        }
    }
#pragma unroll
    for (int cf = 0; cf < 4; ++cf) {
        int col = wc * 64 + cf * 16 + lan;
        float bv; float* dst; int c2;
        if (col < 64) { bv = bl[col]; dst = xl; c2 = col; }
        else          { bv = br[col - 64]; dst = xr; c2 = col - 64; }
#pragma unroll
        for (int rf = 0; rf < 2; ++rf) {
            f32x4 a = rf ? acc1[cf] : acc0[cf];
            int rbase = row0 + wr * 32 + rf * 16 + (l >> 4) * 4;
#pragma unroll
            for (int r = 0; r < 4; ++r) {
                int grow = rbase + r;
                if (grow < n) dst[(size_t)grow * HC + c2] = a[r] + bv;
            }
        }
    }
}

// ---------------- MFMA head GEMM: out = sigmoid(h @ Wo + bo) ----------------
__global__ __launch_bounds__(256) void head_gemm_mfma_k(
        const float* __restrict__ A,
        const unsigned short* __restrict__ img,
        const float* __restrict__ bo,
        float* __restrict__ out, int n) {
    __shared__ __attribute__((aligned(16))) unsigned short As[2][64][40];
    __shared__ __attribute__((aligned(16))) unsigned short Bs[2][128][40];
    int t = threadIdx.x;
    int l = t & 63, w = t >> 6;
    int wr = w >> 1, wc = w & 1;
    int lan = l & 15;
    int kb  = (l >> 4) * 8;
    int row0 = blockIdx.x * 64;
    int coloff = blockIdx.y * 128;
    const unsigned short* himg = img + (size_t)blockIdx.y * 2 * 10240;
    int srow = t >> 2;
    int skq  = (t & 3) * 8;
    bool rok = (row0 + srow) < n;
    const float* aptr = A + (size_t)(row0 + srow) * HC + skq;

    f32x4 acc0[4] = {}, acc1[4] = {};

    for (int ks = 0; ks < 2; ++ks) {
        __syncthreads();
        {
            const ush8* src = (const ush8*)(himg + (size_t)ks * 10240);
            ush8* dst = (ush8*)&Bs[0][0][0];
            int base = w * 5 * 64 + l;
#pragma unroll
            for (int c2 = 0; c2 < 5; ++c2) {
                int u = base + c2 * 64;
                dst[u] = src[u];
            }
        }
        {
            float4 f0 = make_float4(0.f, 0.f, 0.f, 0.f), f1 = f0;
            if (rok) {
                f0 = *(const float4*)(aptr + ks * 32);
                f1 = *(const float4*)(aptr + ks * 32 + 4);
            }
            float xs[8] = {f0.x, f0.y, f0.z, f0.w, f1.x, f1.y, f1.z, f1.w};
            ush8 hi8, lo8;
#pragma unroll
            for (int j = 0; j < 8; ++j) {
                unsigned short h = f2bf(xs[j]);
                hi8[j] = h;
                lo8[j] = f2bf(xs[j] - bf2f(h));
            }
            *(ush8*)&As[0][srow][skq] = hi8;
            *(ush8*)&As[1][srow][skq] = lo8;
        }
        __syncthreads();
        bf16x8 ah0 = *(const bf16x8*)&As[0][wr * 32 + lan][kb];
        bf16x8 ah1 = *(const bf16x8*)&As[0][wr * 32 + 16 + lan][kb];
        bf16x8 al0 = *(const bf16x8*)&As[1][wr * 32 + lan][kb];
        bf16x8 al1 = *(const bf16x8*)&As[1][wr * 32 + 16 + lan][kb];
#pragma unroll
        for (int cf = 0; cf < 4; ++cf) {
            int bc = wc * 64 + cf * 16 + lan;
            bf16x8 bhv = *(const bf16x8*)&Bs[0][bc][kb];
            bf16x8 blv = *(const bf16x8*)&Bs[1][bc][kb];
            acc0[cf] = __builtin_amdgcn_mfma_f32_16x16x32_bf16(ah0, bhv, acc0[cf], 0, 0, 0);
            acc1[cf] = __builtin_amdgcn_mfma_f32_16x16x32_bf16(ah1, bhv, acc1[cf], 0, 0, 0);
            acc0[cf] = __builtin_amdgcn_mfma_f32_16x16x32_bf16(al0, bhv, acc0[cf], 0, 0, 0);
            acc1[cf] = __builtin_amdgcn_mfma_f32_16x16x32_bf16(al1, bhv, acc1[cf], 0, 0, 0);
            acc0[cf] = __builtin_amdgcn_mfma_f32_16x16x32_bf16(ah0, blv, acc0[cf], 0, 0, 0);
            acc1[cf] = __builtin_amdgcn_mfma_f32_16x16x32_bf16(ah1, blv, acc1[cf], 0, 0, 0);
        }
    }
#pragma unroll
    for (int cf = 0; cf < 4; ++cf) {
        int col = coloff + wc * 64 + cf * 16 + lan;
        float bv = bo[col];
#pragma unroll
        for (int rf = 0; rf < 2; ++rf) {
            f32x4 a = rf ? acc1[cf] : acc0[cf];
            int rbase = row0 + wr * 32 + rf * 16 + (l >> 4) * 4;
#pragma unroll
            for (int r = 0; r < 4; ++r) {
                int grow = rbase + r;
                if (grow < n) {
                    float v = a[r] + bv;
                    out[(size_t)grow * DIN + col] = 1.f / (1.f + __expf(-v));
                }
            }
        }
    }
}

// ---------------- edge aggregation v2: 4 edges per wave -------------------
// lane = (q, sl): q = edge slot (0..3), sl = channel group; lane owns float4
// channels sl*4..sl*4+3 (all within head sl>>2 since C=16).
// Per 4 edges: 1 ssb gather + 4 float4 gathers... wait: one dwordx4 gather
// covers ONE edge's channels across 16 lanes; one wave instr covers 4 edges.
// Logit reduce: 4 in-lane FMAs + 2 DPP steps (xor1, xor2 over 4-lane group).
// exp2 with ln2 prefolded into att. Slot partials combined via shfl_xor at end.
#define AGRP(EBASE, FULL)                                                     \
    {                                                                         \
        int e = (EBASE) + q;                                                  \
        bool ok = FULL ? true : (e < hi);                                     \
        int ec = FULL ? e : (ok ? e : (hi - 1));                              \
        unsigned sb = ssb[ec];                                                \
        float4 xv = *(const float4*)(xlb + sb + loff);                        \
        float s0 = xv.x + xrq.x, s1 = xv.y + xrq.y;                           \
        float s2 = xv.z + xrq.z, s3 = xv.w + xrq.w;                           \
        float tt = atq.x * fmaxf(s0, NEG * s0);                               \
        tt = fmaf(atq.y, fmaxf(s1, NEG * s1), tt);                            \
        tt = fmaf(atq.z, fmaxf(s2, NEG * s2), tt);                            \
        tt = fmaf(atq.w, fmaxf(s3, NEG * s3), tt);                            \
        tt += dpp_mov<0xB1>(tt);                                              \
        tt += dpp_mov<0x4E>(tt);                                              \
        float ex = exp2f(tt);                                                 \
        if (!FULL) ex = ok ? ex : 0.f;                                        \
        den += ex;                                                            \
        acc.x = fmaf(ex, xv.x, acc.x); acc.y = fmaf(ex, xv.y, acc.y);         \
        acc.z = fmaf(ex, xv.z, acc.z); acc.w = fmaf(ex, xv.w, acc.w);         \
    }

__global__ __launch_bounds__(256) void agg_k(const float* __restrict__ xl,
                                             const float* __restrict__ xr,
                                             const float* __restrict__ att,
                                             const float* __restrict__ bias,
                                             const int* __restrict__ offs,
                                             const unsigned* __restrict__ ssb,
                                             float* __restrict__ out, int n) {
    int wave = (blockIdx.x * 256 + threadIdx.x) >> 6;
    int lane = threadIdx.x & 63;
    if (wave >= n) return;
    int q  = lane >> 4;
    int sl = lane & 15;
    const char* xlb = (const char*)xl;
    unsigned loff = (unsigned)sl * 16u;
    float4 xrq = *(const float4*)(xr + (size_t)wave * HC + sl * 4);
    float4 atq = *(const float4*)(att + sl * 4);
    const float LOG2E = 1.44269504088896340736f;
    atq.x *= LOG2E; atq.y *= LOG2E; atq.z *= LOG2E; atq.w *= LOG2E;
    float4 acc = make_float4(0.f, 0.f, 0.f, 0.f);
    float den = 0.f;
    int lo = __builtin_amdgcn_readfirstlane(offs[wave]);
    int hi = __builtin_amdgcn_readfirstlane(offs[wave + 1]);
    int i = lo;
    for (; i + 16 <= hi; i += 16) {
        AGRP(i, true) AGRP(i + 4, true) AGRP(i + 8, true) AGRP(i + 12, true)
    }
    for (; i < hi; i += 4) {
        AGRP(i, false)
    }
    // combine the 4 edge slots: lanes {sl, sl+16, sl+32, sl+48}
#pragma unroll
    for (int m = 16; m < 64; m <<= 1) {
        acc.x += __shfl_xor(acc.x, m);
        acc.y += __shfl_xor(acc.y, m);
        acc.z += __shfl_xor(acc.z, m);
        acc.w += __shfl_xor(acc.w, m);
        den   += __shfl_xor(den, m);
    }
    if (q == 0) {
        float r = (den > 0.f) ? 1.f / den : 0.f;
        float4 b4 = *(const float4*)(bias + sl * 4);
        float4 o;
        o.x = fmaxf(fmaf(acc.x, r, b4.x), 0.f);
        o.y = fmaxf(fmaf(acc.y, r, b4.y), 0.f);
        o.z = fmaxf(fmaf(acc.z, r, b4.z), 0.f);
        o.w = fmaxf(fmaf(acc.w, r, b4.w), 0.f);
        *(float4*)(out + (size_t)wave * HC + sl * 4) = o;
    }
}

extern "C" void kernel_launch(void* const* d_in, const int* in_sizes, int n_in,
                              void* d_out, int out_size, void* d_ws, size_t ws_size,
                              hipStream_t stream) {
    const float* x    = (const float*)d_in[0];
    const int*   ei   = (const int*)d_in[1];
    const float* Wl1  = (const float*)d_in[2];
    const float* bl1  = (const float*)d_in[3];
    const float* Wr1  = (const float*)d_in[4];
    const float* br1  = (const float*)d_in[5];
    const float* att1 = (const float*)d_in[6];
    const float* bias1= (const float*)d_in[7];
    const float* Wl2  = (const float*)d_in[8];
    const float* bl2  = (const float*)d_in[9];
    const float* Wr2  = (const float*)d_in[10];
    const float* br2  = (const float*)d_in[11];
    const float* att2 = (const float*)d_in[12];
    const float* bias2= (const float*)d_in[13];
    const float* Wo   = (const float*)d_in[14];
    const float* bo   = (const float*)d_in[15];
    float* out = (float*)d_out;

    int E = in_sizes[1] / 2;
    const int* srcv = ei;
    const int* dstv = ei + E;

    size_t NF = (size_t)NN * HC;
    float* xl = (float*)d_ws;
    float* xr = xl + NF;
    float* hb = xr + NF;                  // h1, later h2
    int* offs        = (int*)(hb + NF);   // NN+1
    unsigned* ssrc   = (unsigned*)(offs + NN + 1);  // E (byte offsets)
    int* boffs   = (int*)(ssrc + E);      // NB+1
    int* bcursor = boffs + NB + 1;        // NB
    int* bcnt    = bcursor + NB;          // NB
    unsigned* epair = (unsigned*)d_out;
    unsigned short* img1 = (unsigned short*)d_out;   // 81920 ush = 160 KB
    unsigned short* img2 = img1 + 81920;             // 20480 ush = 40 KB
    unsigned short* imgh = (unsigned short*)xl;      // 40960 ush, after agg2

    hipMemsetAsync(bcnt, 0, NB * sizeof(int), stream);
    bhist_k<<<(E + 2047) / 2048, 256, 0, stream>>>(dstv, bcnt, E);
    bscan_k<<<1, 256, 0, stream>>>(bcnt, boffs, bcursor, offs, E);
    bin_k<<<(E + EPB - 1) / EPB, 1024, 0, stream>>>(srcv, dstv, bcursor, epair, E);
    bsort_k<<<NB, 1024, 0, stream>>>(epair, boffs, offs, ssrc, NN);
    wprep_dual_k<<<320, 256, 0, stream>>>(Wl1, Wr1, img1, DIN);
    wprep_dual_k<<<80, 256, 0, stream>>>(Wl2, Wr2, img2, HC);

    int gb = (NN + TM - 1) / TM;
    // layer 1
    gemm_dual_mfma_k<<<gb, 256, 0, stream>>>(x, img1, bl1, br1, xl, xr, NN, DIN);
    agg_k<<<(NN + 3) / 4, 256, 0, stream>>>(xl, xr, att1, bias1, offs, ssrc, hb, NN);
    // layer 2
    gemm_dual_mfma_k<<<gb, 256, 0, stream>>>(hb, img2, bl2, br2, xl, xr, NN, HC);
    agg_k<<<(NN + 3) / 4, 256, 0, stream>>>(xl, xr, att2, bias2, offs, ssrc, hb, NN);
    // head (xl region free -> holds Wo image)
    wprep_head_k<<<160, 256, 0, stream>>>(Wo, imgh);
    head_gemm_mfma_k<<<dim3(gb, 2), 256, 0, stream>>>(hb, imgh, bo, out, NN);
}

// Round 3
// 319.671 us; speedup vs baseline: 1.0967x; 1.0967x over previous
//
#include <hip/hip_runtime.h>
#include <math.h>

#define NN 50000
#define DIN 256
#define HC 64
#define NEG 0.2f
#define TM 64
#define NB 196          // ceil(NN/256) coarse buckets (dst >> 8)
#define EPB 4096        // edges per bin_k block
#define CAP 36864       // bsort LDS staging capacity

typedef short bf16x8 __attribute__((ext_vector_type(8)));
typedef unsigned short ush8 __attribute__((ext_vector_type(8)));
typedef float f32x4 __attribute__((ext_vector_type(4)));

// fp32 -> bf16 round-to-nearest-even
__device__ __forceinline__ unsigned short f2bf(float x) {
    unsigned u = __float_as_uint(x);
    u += 0x7FFFu + ((u >> 16) & 1u);
    return (unsigned short)(u >> 16);
}
__device__ __forceinline__ float bf2f(unsigned short h) {
    return __uint_as_float((unsigned)h << 16);
}

// ---- DPP cross-lane add helper ----
template <int CTRL>
__device__ __forceinline__ float dpp_mov(float x) {
    int r = __builtin_amdgcn_update_dpp(0, __float_as_int(x), CTRL, 0xF, 0xF, true);
    return __int_as_float(r);
}

// ---------------- CSR build: bucketed counting sort ----------------

__global__ __launch_bounds__(256) void bhist_k(const int* __restrict__ dst,
                                               int* __restrict__ bcnt, int E) {
    __shared__ int h[NB];
    int t = threadIdx.x;
    for (int i = t; i < NB; i += 256) h[i] = 0;
    __syncthreads();
    int base = blockIdx.x * 2048 + t;
#pragma unroll
    for (int k = 0; k < 8; ++k) {
        int e = base + k * 256;
        if (e < E) atomicAdd(&h[dst[e] >> 8], 1);
    }
    __syncthreads();
    for (int i = t; i < NB; i += 256)
        if (h[i]) atomicAdd(&bcnt[i], h[i]);
}

__global__ __launch_bounds__(256) void bscan_k(const int* __restrict__ bcnt,
                                               int* __restrict__ boffs,
                                               int* __restrict__ bcursor,
                                               int* __restrict__ offs, int E) {
    __shared__ int s[256];
    int t = threadIdx.x;
    s[t] = (t < NB) ? bcnt[t] : 0;
    __syncthreads();
    for (int off = 1; off < 256; off <<= 1) {
        int v = s[t];
        int u = (t >= off) ? s[t - off] : 0;
        __syncthreads();
        s[t] = v + u;
        __syncthreads();
    }
    if (t < NB) {
        int ex = (t == 0) ? 0 : s[t - 1];
        boffs[t] = ex;
        bcursor[t] = ex;
    }
    if (t == NB) boffs[NB] = s[NB - 1];
    if (t == 0) offs[NN] = E;
}

__global__ __launch_bounds__(1024) void bin_k(const int* __restrict__ src,
                                              const int* __restrict__ dst,
                                              int* __restrict__ bcursor,
                                              unsigned* __restrict__ epair, int E) {
    __shared__ int hist[NB];
    __shared__ int lofs[NB];
    __shared__ int gshift[NB];
    __shared__ int scanb[256];
    __shared__ unsigned pbuf[EPB];
    __shared__ unsigned char abkt[EPB];
    int t = threadIdx.x;
    for (int i = t; i < NB; i += 1024) hist[i] = 0;
    __syncthreads();
    int e0 = blockIdx.x * EPB;
    unsigned p[4]; int bk[4], rk[4]; bool val[4];
#pragma unroll
    for (int k = 0; k < 4; ++k) {
        int e = e0 + k * 1024 + t;
        val[k] = e < E;
        if (val[k]) {
            int s = src[e], d = dst[e];
            p[k] = ((unsigned)s << 8) | (unsigned)(d & 255);
            bk[k] = d >> 8;
            rk[k] = atomicAdd(&hist[bk[k]], 1);
        }
    }
    __syncthreads();
    if (t < 256) scanb[t] = (t < NB) ? hist[t] : 0;
    __syncthreads();
    for (int off = 1; off < 256; off <<= 1) {
        int v = 0, u = 0;
        if (t < 256) { v = scanb[t]; if (t >= off) u = scanb[t - off]; }
        __syncthreads();
        if (t < 256) scanb[t] = v + u;
        __syncthreads();
    }
    if (t < NB) {
        int ex = (t == 0) ? 0 : scanb[t - 1];
        lofs[t] = ex;
        int gb = atomicAdd(&bcursor[t], hist[t]);
        gshift[t] = gb - ex;
    }
    __syncthreads();
    int total = scanb[NB - 1];
#pragma unroll
    for (int k = 0; k < 4; ++k) {
        if (val[k]) {
            int pos = lofs[bk[k]] + rk[k];
            pbuf[pos] = p[k];
            abkt[pos] = (unsigned char)bk[k];
        }
    }
    __syncthreads();
    for (int i = t; i < total; i += 1024) {
        int b = abkt[i];
        epair[gshift[b] + i] = pbuf[i];
    }
}

// per-bucket counting sort; ssrc holds HALF-BYTE offsets (src*HC*2 == src<<7)
__global__ __launch_bounds__(1024) void bsort_k(const unsigned* __restrict__ epair,
                                                const int* __restrict__ boffs,
                                                int* __restrict__ offs,
                                                unsigned* __restrict__ ssrc, int n) {
    __shared__ int lhist[256];
    __shared__ int lcur[256];
    __shared__ int scanb[256];
    __shared__ unsigned sbuf[CAP];
    int b = blockIdx.x, t = threadIdx.x;
    int start = boffs[b], end = boffs[b + 1];
    int cnt = end - start;
    if (t < 256) lhist[t] = 0;
    __syncthreads();
    for (int i = t; i < cnt; i += 1024) {
        unsigned p = epair[start + i];
        atomicAdd(&lhist[p & 255], 1);
    }
    __syncthreads();
    if (t < 256) scanb[t] = lhist[t];
    __syncthreads();
    for (int off = 1; off < 256; off <<= 1) {
        int v = 0, u = 0;
        if (t < 256) { v = scanb[t]; if (t >= off) u = scanb[t - off]; }
        __syncthreads();
        if (t < 256) scanb[t] = v + u;
        __syncthreads();
    }
    if (t < 256) {
        int ex = (t == 0) ? 0 : scanb[t - 1];
        lcur[t] = ex;
        int node = b * 256 + t;
        if (node < n) offs[node] = start + ex;
    }
    __syncthreads();
    if (cnt <= CAP) {
        for (int i = t; i < cnt; i += 1024) {
            unsigned p = epair[start + i];
            int r = atomicAdd(&lcur[p & 255], 1);
            sbuf[r] = p & ~255u;
        }
        __syncthreads();
        for (int i = t; i < cnt; i += 1024) ssrc[start + i] = sbuf[i] >> 1;
    } else {
        for (int i = t; i < cnt; i += 1024) {
            unsigned p = epair[start + i];
            int r = atomicAdd(&lcur[p & 255], 1);
            ssrc[start + r] = (p & ~255u) >> 1;
        }
    }
}

// ---------------- weight prep: transpose + bf16 hi/lo split ----------------
__global__ __launch_bounds__(256) void wprep_dual_k(const float* __restrict__ Wl,
                                                    const float* __restrict__ Wr,
                                                    unsigned short* __restrict__ img,
                                                    int K) {
    int i = blockIdx.x * 256 + threadIdx.x;
    int total = (K >> 5) * 10240;
    if (i >= total) return;
    int kk = i % 40;
    int c  = (i / 40) & 127;
    int p  = (i / 5120) & 1;
    int s  = i / 10240;
    unsigned short v = 0;
    if (kk < 32) {
        int k = s * 32 + kk;
        float w = (c < 64) ? Wl[k * HC + c] : Wr[k * HC + (c - 64)];
        unsigned short hi = f2bf(w);
        v = p ? f2bf(w - bf2f(hi)) : hi;
    }
    img[i] = v;
}

__global__ __launch_bounds__(256) void wprep_head_k(const float* __restrict__ Wo,
                                                    unsigned short* __restrict__ img) {
    int i = blockIdx.x * 256 + threadIdx.x;
    if (i >= 40960) return;
    int kk = i % 40;
    int c  = (i / 40) & 127;
    int p  = (i / 5120) & 1;
    int s  = (i / 10240) & 1;
    int h  = i / 20480;
    unsigned short v = 0;
    if (kk < 32) {
        int k = s * 32 + kk;
        float w = Wo[k * DIN + h * 128 + c];
        unsigned short hi = f2bf(w);
        v = p ? f2bf(w - bf2f(hi)) : hi;
    }
    img[i] = v;
}

// ---------------- MFMA dual GEMM: [xlh|xr] = A @ [Wl|Wr] + [bl|br] ----------
// xl side stored as fp16 mirror only (gather target); xr side fp32.
__global__ __launch_bounds__(256) void gemm_dual_mfma_k(
        const float* __restrict__ A,
        const unsigned short* __restrict__ img,
        const float* __restrict__ bl, const float* __restrict__ br,
        _Float16* __restrict__ xlh, float* __restrict__ xr,
        int n, int K) {
    __shared__ __attribute__((aligned(16))) unsigned short As[2][64][40];
    __shared__ __attribute__((aligned(16))) unsigned short Bs[2][128][40];
    int t = threadIdx.x;
    int l = t & 63, w = t >> 6;
    int wr = w >> 1, wc = w & 1;
    int lan = l & 15;
    int kb  = (l >> 4) * 8;
    int row0 = blockIdx.x * 64;
    int srow = t >> 2;
    int skq  = (t & 3) * 8;
    bool rok = (row0 + srow) < n;
    const float* aptr = A + (size_t)(row0 + srow) * K + skq;

    f32x4 acc0[4] = {}, acc1[4] = {};

    int nks = K >> 5;
    for (int ks = 0; ks < nks; ++ks) {
        __syncthreads();
        {
            const ush8* src = (const ush8*)(img + (size_t)ks * 10240);
            ush8* dst = (ush8*)&Bs[0][0][0];
            int base = w * 5 * 64 + l;
#pragma unroll
            for (int c2 = 0; c2 < 5; ++c2) {
                int u = base + c2 * 64;
                dst[u] = src[u];
            }
        }
        {
            float4 f0 = make_float4(0.f, 0.f, 0.f, 0.f), f1 = f0;
            if (rok) {
                f0 = *(const float4*)(aptr + ks * 32);
                f1 = *(const float4*)(aptr + ks * 32 + 4);
            }
            float xs[8] = {f0.x, f0.y, f0.z, f0.w, f1.x, f1.y, f1.z, f1.w};
            ush8 hi8, lo8;
#pragma unroll
            for (int j = 0; j < 8; ++j) {
                unsigned short h = f2bf(xs[j]);
                hi8[j] = h;
                lo8[j] = f2bf(xs[j] - bf2f(h));
            }
            *(ush8*)&As[0][srow][skq] = hi8;
            *(ush8*)&As[1][srow][skq] = lo8;
        }
        __syncthreads();
        bf16x8 ah0 = *(const bf16x8*)&As[0][wr * 32 + lan][kb];
        bf16x8 ah1 = *(const bf16x8*)&As[0][wr * 32 + 16 + lan][kb];
        bf16x8 al0 = *(const bf16x8*)&As[1][wr * 32 + lan][kb];
        bf16x8 al1 = *(const bf16x8*)&As[1][wr * 32 + 16 + lan][kb];
#pragma unroll
        for (int cf = 0; cf < 4; ++cf) {
            int bc = wc * 64 + cf * 16 + lan;
            bf16x8 bhv = *(const bf16x8*)&Bs[0][bc][kb];
            bf16x8 blv = *(const bf16x8*)&Bs[1][bc][kb];
            acc0[cf] = __builtin_amdgcn_mfma_f32_16x16x32_bf16(ah0, bhv, acc0[cf], 0, 0, 0);
            acc1[cf] = __builtin_amdgcn_mfma_f32_16x16x32_bf16(ah1, bhv, acc1[cf], 0, 0, 0);
            acc0[cf] = __builtin_amdgcn_mfma_f32_16x16x32_bf16(al0, bhv, acc0[cf], 0, 0, 0);
            acc1[cf] = __builtin_amdgcn_mfma_f32_16x16x32_bf16(al1, bhv, acc1[cf], 0, 0, 0);
            acc0[cf] = __builtin_amdgcn_mfma_f32_16x16x32_bf16(ah0, blv, acc0[cf], 0, 0, 0);
            acc1[cf] = __builtin_amdgcn_mfma_f32_16x16x32_bf16(ah1, blv, acc1[cf], 0, 0, 0);
        }
    }
#pragma unroll
    for (int cf = 0; cf < 4; ++cf) {
        int col = wc * 64 + cf * 16 + lan;
        bool left = col < 64;
        float bv = left ? bl[col] : br[col - 64];
        int c2 = left ? col : col - 64;
#pragma unroll
        for (int rf = 0; rf < 2; ++rf) {
            f32x4 a = rf ? acc1[cf] : acc0[cf];
            int rbase = row0 + wr * 32 + rf * 16 + (l >> 4) * 4;
#pragma unroll
            for (int r = 0; r < 4; ++r) {
                int grow = rbase + r;
                if (grow < n) {
                    float v = a[r] + bv;
                    if (left) xlh[(size_t)grow * HC + c2] = (_Float16)v;
                    else      xr[(size_t)grow * HC + c2] = v;
                }
            }
        }
    }
}

// ---------------- MFMA head GEMM: out = sigmoid(h @ Wo + bo) ----------------
__global__ __launch_bounds__(256) void head_gemm_mfma_k(
        const float* __restrict__ A,
        const unsigned short* __restrict__ img,
        const float* __restrict__ bo,
        float* __restrict__ out, int n) {
    __shared__ __attribute__((aligned(16))) unsigned short As[2][64][40];
    __shared__ __attribute__((aligned(16))) unsigned short Bs[2][128][40];
    int t = threadIdx.x;
    int l = t & 63, w = t >> 6;
    int wr = w >> 1, wc = w & 1;
    int lan = l & 15;
    int kb  = (l >> 4) * 8;
    int row0 = blockIdx.x * 64;
    int coloff = blockIdx.y * 128;
    const unsigned short* himg = img + (size_t)blockIdx.y * 2 * 10240;
    int srow = t >> 2;
    int skq  = (t & 3) * 8;
    bool rok = (row0 + srow) < n;
    const float* aptr = A + (size_t)(row0 + srow) * HC + skq;

    f32x4 acc0[4] = {}, acc1[4] = {};

    for (int ks = 0; ks < 2; ++ks) {
        __syncthreads();
        {
            const ush8* src = (const ush8*)(himg + (size_t)ks * 10240);
            ush8* dst = (ush8*)&Bs[0][0][0];
            int base = w * 5 * 64 + l;
#pragma unroll
            for (int c2 = 0; c2 < 5; ++c2) {
                int u = base + c2 * 64;
                dst[u] = src[u];
            }
        }
        {
            float4 f0 = make_float4(0.f, 0.f, 0.f, 0.f), f1 = f0;
            if (rok) {
                f0 = *(const float4*)(aptr + ks * 32);
                f1 = *(const float4*)(aptr + ks * 32 + 4);
            }
            float xs[8] = {f0.x, f0.y, f0.z, f0.w, f1.x, f1.y, f1.z, f1.w};
            ush8 hi8, lo8;
#pragma unroll
            for (int j = 0; j < 8; ++j) {
                unsigned short h = f2bf(xs[j]);
                hi8[j] = h;
                lo8[j] = f2bf(xs[j] - bf2f(h));
            }
            *(ush8*)&As[0][srow][skq] = hi8;
            *(ush8*)&As[1][srow][skq] = lo8;
        }
        __syncthreads();
        bf16x8 ah0 = *(const bf16x8*)&As[0][wr * 32 + lan][kb];
        bf16x8 ah1 = *(const bf16x8*)&As[0][wr * 32 + 16 + lan][kb];
        bf16x8 al0 = *(const bf16x8*)&As[1][wr * 32 + lan][kb];
        bf16x8 al1 = *(const bf16x8*)&As[1][wr * 32 + 16 + lan][kb];
#pragma unroll
        for (int cf = 0; cf < 4; ++cf) {
            int bc = wc * 64 + cf * 16 + lan;
            bf16x8 bhv = *(const bf16x8*)&Bs[0][bc][kb];
            bf16x8 blv = *(const bf16x8*)&Bs[1][bc][kb];
            acc0[cf] = __builtin_amdgcn_mfma_f32_16x16x32_bf16(ah0, bhv, acc0[cf], 0, 0, 0);
            acc1[cf] = __builtin_amdgcn_mfma_f32_16x16x32_bf16(ah1, bhv, acc1[cf], 0, 0, 0);
            acc0[cf] = __builtin_amdgcn_mfma_f32_16x16x32_bf16(al0, bhv, acc0[cf], 0, 0, 0);
            acc1[cf] = __builtin_amdgcn_mfma_f32_16x16x32_bf16(al1, bhv, acc1[cf], 0, 0, 0);
            acc0[cf] = __builtin_amdgcn_mfma_f32_16x16x32_bf16(ah0, blv, acc0[cf], 0, 0, 0);
            acc1[cf] = __builtin_amdgcn_mfma_f32_16x16x32_bf16(ah1, blv, acc1[cf], 0, 0, 0);
        }
    }
#pragma unroll
    for (int cf = 0; cf < 4; ++cf) {
        int col = coloff + wc * 64 + cf * 16 + lan;
        float bv = bo[col];
#pragma unroll
        for (int rf = 0; rf < 2; ++rf) {
            f32x4 a = rf ? acc1[cf] : acc0[cf];
            int rbase = row0 + wr * 32 + rf * 16 + (l >> 4) * 4;
#pragma unroll
            for (int r = 0; r < 4; ++r) {
                int grow = rbase + r;
                if (grow < n) {
                    float v = a[r] + bv;
                    out[(size_t)grow * DIN + col] = 1.f / (1.f + __expf(-v));
                }
            }
        }
    }
}

// ---------------- edge aggregation v3: fp16 gather, 4 edges/wave ----------
// lane = (q, sl): q = edge slot, sl = channel group (4 half channels, 8 B).
// ssrc pre-shifted: entry = src*128 (byte offset into fp16 row of 128 B).
// One 64-lane ssrc load feeds 8 AGRP groups via ds_bpermute.
union H4 { uint2 u; _Float16 h[4]; };

#define AGRP_BODY(SB)                                                         \
    {                                                                         \
        H4 cv;                                                                \
        cv.u = *(const uint2*)(xhb + (SB) + hoff);                            \
        float xv0 = (float)cv.h[0], xv1 = (float)cv.h[1];                     \
        float xv2 = (float)cv.h[2], xv3 = (float)cv.h[3];                     \
        float s0 = xv0 + xrq.x, s1 = xv1 + xrq.y;                             \
        float s2 = xv2 + xrq.z, s3 = xv3 + xrq.w;                             \
        float tt = atq.x * fmaxf(s0, NEG * s0);                               \
        tt = fmaf(atq.y, fmaxf(s1, NEG * s1), tt);                            \
        tt = fmaf(atq.z, fmaxf(s2, NEG * s2), tt);                            \
        tt = fmaf(atq.w, fmaxf(s3, NEG * s3), tt);                            \
        tt += dpp_mov<0xB1>(tt);                                              \
        tt += dpp_mov<0x4E>(tt);                                              \
        float ex = exp2f(tt);                                                 \
        den += ex;                                                            \
        acc.x = fmaf(ex, xv0, acc.x); acc.y = fmaf(ex, xv1, acc.y);           \
        acc.z = fmaf(ex, xv2, acc.z); acc.w = fmaf(ex, xv3, acc.w);           \
    }

#define AGRPS(KK)                                                             \
    {                                                                         \
        unsigned sb = (unsigned)__shfl((int)sbv, (KK) * 4 + q);               \
        AGRP_BODY(sb)                                                         \
    }

__global__ __launch_bounds__(256) void agg_k(const _Float16* __restrict__ xlh,
                                             const float* __restrict__ xr,
                                             const float* __restrict__ att,
                                             const float* __restrict__ bias,
                                             const int* __restrict__ offs,
                                             const unsigned* __restrict__ ssb,
                                             float* __restrict__ out, int n) {
    int wave = (blockIdx.x * 256 + threadIdx.x) >> 6;
    int lane = threadIdx.x & 63;
    if (wave >= n) return;
    int q  = lane >> 4;
    int sl = lane & 15;
    const char* xhb = (const char*)xlh;
    unsigned hoff = (unsigned)sl * 8u;
    float4 xrq = *(const float4*)(xr + (size_t)wave * HC + sl * 4);
    float4 atq = *(const float4*)(att + sl * 4);
    const float LOG2E = 1.44269504088896340736f;
    atq.x *= LOG2E; atq.y *= LOG2E; atq.z *= LOG2E; atq.w *= LOG2E;
    float4 acc = make_float4(0.f, 0.f, 0.f, 0.f);
    float den = 0.f;
    int lo = __builtin_amdgcn_readfirstlane(offs[wave]);
    int hi = __builtin_amdgcn_readfirstlane(offs[wave + 1]);
    int i = lo;
    for (; i + 32 <= hi; i += 32) {
        unsigned sbv = ssb[i + (lane & 31)];
        AGRPS(0) AGRPS(1) AGRPS(2) AGRPS(3)
        AGRPS(4) AGRPS(5) AGRPS(6) AGRPS(7)
    }
    for (; i + 16 <= hi; i += 16) {
        unsigned sbv = ssb[i + (lane & 15)];
        AGRPS(0) AGRPS(1) AGRPS(2) AGRPS(3)
    }
    for (; i < hi; i += 4) {
        int e = i + q;
        bool ok = e < hi;
        int ec = ok ? e : (hi - 1);
        unsigned sb = ssb[ec];
        H4 cv;
        cv.u = *(const uint2*)(xhb + sb + hoff);
        float xv0 = (float)cv.h[0], xv1 = (float)cv.h[1];
        float xv2 = (float)cv.h[2], xv3 = (float)cv.h[3];
        float s0 = xv0 + xrq.x, s1 = xv1 + xrq.y;
        float s2 = xv2 + xrq.z, s3 = xv3 + xrq.w;
        float tt = atq.x * fmaxf(s0, NEG * s0);
        tt = fmaf(atq.y, fmaxf(s1, NEG * s1), tt);
        tt = fmaf(atq.z, fmaxf(s2, NEG * s2), tt);
        tt = fmaf(atq.w, fmaxf(s3, NEG * s3), tt);
        tt += dpp_mov<0xB1>(tt);
        tt += dpp_mov<0x4E>(tt);
        float ex = exp2f(tt);
        ex = ok ? ex : 0.f;
        den += ex;
        acc.x = fmaf(ex, xv0, acc.x); acc.y = fmaf(ex, xv1, acc.y);
        acc.z = fmaf(ex, xv2, acc.z); acc.w = fmaf(ex, xv3, acc.w);
    }
    // combine the 4 edge slots: lanes {sl, sl+16, sl+32, sl+48}
#pragma unroll
    for (int m = 16; m < 64; m <<= 1) {
        acc.x += __shfl_xor(acc.x, m);
        acc.y += __shfl_xor(acc.y, m);
        acc.z += __shfl_xor(acc.z, m);
        acc.w += __shfl_xor(acc.w, m);
        den   += __shfl_xor(den, m);
    }
    if (q == 0) {
        float r = (den > 0.f) ? 1.f / den : 0.f;
        float4 b4 = *(const float4*)(bias + sl * 4);
        float4 o;
        o.x = fmaxf(fmaf(acc.x, r, b4.x), 0.f);
        o.y = fmaxf(fmaf(acc.y, r, b4.y), 0.f);
        o.z = fmaxf(fmaf(acc.z, r, b4.z), 0.f);
        o.w = fmaxf(fmaf(acc.w, r, b4.w), 0.f);
        *(float4*)(out + (size_t)wave * HC + sl * 4) = o;
    }
}

extern "C" void kernel_launch(void* const* d_in, const int* in_sizes, int n_in,
                              void* d_out, int out_size, void* d_ws, size_t ws_size,
                              hipStream_t stream) {
    const float* x    = (const float*)d_in[0];
    const int*   ei   = (const int*)d_in[1];
    const float* Wl1  = (const float*)d_in[2];
    const float* bl1  = (const float*)d_in[3];
    const float* Wr1  = (const float*)d_in[4];
    const float* br1  = (const float*)d_in[5];
    const float* att1 = (const float*)d_in[6];
    const float* bias1= (const float*)d_in[7];
    const float* Wl2  = (const float*)d_in[8];
    const float* bl2  = (const float*)d_in[9];
    const float* Wr2  = (const float*)d_in[10];
    const float* br2  = (const float*)d_in[11];
    const float* att2 = (const float*)d_in[12];
    const float* bias2= (const float*)d_in[13];
    const float* Wo   = (const float*)d_in[14];
    const float* bo   = (const float*)d_in[15];
    float* out = (float*)d_out;

    int E = in_sizes[1] / 2;
    const int* srcv = ei;
    const int* dstv = ei + E;

    size_t NF = (size_t)NN * HC;
    float* xl = (float*)d_ws;             // region kept (imgh lives here)
    float* xr = xl + NF;
    float* hb = xr + NF;                  // h1, later h2
    int* offs        = (int*)(hb + NF);   // NN+1
    unsigned* ssrc   = (unsigned*)(offs + NN + 1);  // E (pre-shifted fp16 offsets)
    int* boffs   = (int*)(ssrc + E);      // NB+1
    int* bcursor = boffs + NB + 1;        // NB
    int* bcnt    = bcursor + NB;          // NB
    // d_out scratch: epair (first 6.4 MB) consumed by bsort_k; weight imgs
    // (first 200 KB) consumed before head_gemm; xlh at +16 MB consumed by
    // agg2 before head_gemm writes out.
    unsigned* epair = (unsigned*)d_out;
    unsigned short* img1 = (unsigned short*)d_out;   // 81920 ush = 160 KB
    unsigned short* img2 = img1 + 81920;             // 20480 ush = 40 KB
    unsigned short* imgh = (unsigned short*)xl;      // 40960 ush, after agg2
    _Float16* xlh = (_Float16*)((char*)d_out + (16u << 20));  // 6.4 MB

    hipMemsetAsync(bcnt, 0, NB * sizeof(int), stream);
    bhist_k<<<(E + 2047) / 2048, 256, 0, stream>>>(dstv, bcnt, E);
    bscan_k<<<1, 256, 0, stream>>>(bcnt, boffs, bcursor, offs, E);
    bin_k<<<(E + EPB - 1) / EPB, 1024, 0, stream>>>(srcv, dstv, bcursor, epair, E);
    bsort_k<<<NB, 1024, 0, stream>>>(epair, boffs, offs, ssrc, NN);
    wprep_dual_k<<<320, 256, 0, stream>>>(Wl1, Wr1, img1, DIN);
    wprep_dual_k<<<80, 256, 0, stream>>>(Wl2, Wr2, img2, HC);

    int gb = (NN + TM - 1) / TM;
    // layer 1
    gemm_dual_mfma_k<<<gb, 256, 0, stream>>>(x, img1, bl1, br1, xlh, xr, NN, DIN);
    agg_k<<<(NN + 3) / 4, 256, 0, stream>>>(xlh, xr, att1, bias1, offs, ssrc, hb, NN);
    // layer 2
    gemm_dual_mfma_k<<<gb, 256, 0, stream>>>(hb, img2, bl2, br2, xlh, xr, NN, HC);
    agg_k<<<(NN + 3) / 4, 256, 0, stream>>>(xlh, xr, att2, bias2, offs, ssrc, hb, NN);
    // head (xl region free -> holds Wo image)
    wprep_head_k<<<160, 256, 0, stream>>>(Wo, imgh);
    head_gemm_mfma_k<<<dim3(gb, 2), 256, 0, stream>>>(hb, imgh, bo, out, NN);
}